// Round 2
// baseline (5243.132 us; speedup 1.0000x reference)
//
#include <hip/hip_runtime.h>
#include <stdint.h>

#define DEPTH 20
#define FEAT  2048
#define HALF  1024
#define HID   1024
#define MROWS 4096

typedef __bf16 bf16x8 __attribute__((ext_vector_type(8)));
typedef float  f32x4  __attribute__((ext_vector_type(4)));
typedef unsigned int u32x4 __attribute__((ext_vector_type(4)));

__device__ __forceinline__ unsigned short f2bf(float f) {
  union { float f; unsigned int u; } v; v.f = f;
  unsigned int u = v.u + 0x7fffu + ((v.u >> 16) & 1u);
  return (unsigned short)(u >> 16);
}

__device__ __forceinline__ void async_cp16(unsigned short* lds, const unsigned short* g) {
  __builtin_amdgcn_global_load_lds(
      (const __attribute__((address_space(1))) void*)g,
      (__attribute__((address_space(3))) void*)lds, 16, 0, 0);
}

__device__ __forceinline__ bf16x8 lds_ld8(const unsigned short* p) {
  return __builtin_bit_cast(bf16x8, *(const u32x4*)p);
}

// ---------------------------------------------------------------------------
// Batched weight transpose + cvt: src[k][n] fp32 -> dst[n'][k] bf16.
// 64-k x 32-n tiles, ushort2 stores (G13: vectorize the 2B write path).
// For HID->FEAT matrices (pp=1) output rows are pair-permuted:
//   orig n<1024:  p = 64*(n/32) + (n%32)
//   orig n>=1024: p = 64*((n-1024)/32) + 32 + ((n-1024)%32)
// ---------------------------------------------------------------------------
__global__ void wcvt_k(const float* __restrict__ s2w1, const float* __restrict__ s2w2,
                       const float* __restrict__ s1w1, const float* __restrict__ s1w2,
                       unsigned short* __restrict__ w2a, unsigned short* __restrict__ w2b,
                       unsigned short* __restrict__ w1a, unsigned short* __restrict__ w1b) {
  const int zid = blockIdx.z;           // 0..79 : 20 depths x 4 matrices
  const int d = zid >> 2, which = zid & 3;
  const float* src; unsigned short* dst; int N, pp;
  switch (which) {
    case 0:  src = s2w1 + (size_t)d * HALF * HID;  dst = w2a + (size_t)d * HALF * HID; N = 1024; pp = 0; break;
    case 1:  src = s2w2 + (size_t)d * HID * FEAT;  dst = w2b + (size_t)d * FEAT * HID; N = 2048; pp = 1; break;
    case 2:  src = s1w1 + (size_t)d * HALF * HID;  dst = w1a + (size_t)d * HALF * HID; N = 1024; pp = 0; break;
    default: src = s1w2 + (size_t)d * HID * FEAT;  dst = w1b + (size_t)d * FEAT * HID; N = 2048; pp = 1; break;
  }
  int nb = blockIdx.x * 32;
  if (nb >= N) return;
  int kb = blockIdx.y * 64;
  __shared__ float t[64][33];
  int tx = threadIdx.x, ty = threadIdx.y;
#pragma unroll
  for (int s = 0; s < 8; ++s)
    t[ty + 8*s][tx] = src[(size_t)(kb + ty + 8*s) * N + nb + tx];
  __syncthreads();
  int pbase = pp ? (nb < 1024 ? 2*nb : 2*(nb - 1024) + 32) : nb;
#pragma unroll
  for (int s = 0; s < 4; ++s) {
    int nl = ty + 8*s;
    ushort2 w;
    w.x = f2bf(t[2*tx][nl]);
    w.y = f2bf(t[2*tx + 1][nl]);
    *(ushort2*)&dst[(size_t)(pbase + nl) * 1024 + kb + 2*tx] = w;
  }
}

__device__ __forceinline__ int porig(int p) {
  int g = p >> 6, o = p & 63;
  return (o < 32) ? (g*32 + o) : (1024 + g*32 + (o - 32));
}

// Batched over all depths: i in [0, 20*6144)
__global__ void bias_k(const float* __restrict__ s2b1, const float* __restrict__ s2b2,
                       const float* __restrict__ s1b1, const float* __restrict__ s1b2,
                       float* __restrict__ b2a, float* __restrict__ b2b,
                       float* __restrict__ b1a, float* __restrict__ b1b) {
  int i = blockIdx.x * 256 + threadIdx.x;
  if (i >= DEPTH * 6144) return;
  int d = i / 6144, j = i - d * 6144;
  if (j < 1024)      b2a[d*1024 + j] = s2b1[(size_t)d*HID + j];
  else if (j < 3072) { int p = j - 1024; b2b[d*2048 + p] = s2b2[(size_t)d*FEAT + porig(p)]; }
  else if (j < 4096) b1a[d*1024 + j - 3072] = s1b1[(size_t)d*HID + j - 3072];
  else               { int p = j - 4096; b1b[d*2048 + p] = s1b2[(size_t)d*FEAT + porig(p)]; }
}

// inverse perms for all depths: invp[d][perm[d][c]] = c
__global__ void invp_k(const int* __restrict__ perms, int* __restrict__ invp) {
  int i = blockIdx.x * 256 + threadIdx.x;   // 20*2048 = 40960
  if (i >= DEPTH * FEAT) return;
  int d = i >> 11, c = i & 2047;
  invp[(d << 11) | perms[i]] = c;
}

// depth-0 only: x -> permuted split: x1 fp32, x2 fp32 + bf16
__global__ void permute_k(const float* __restrict__ z, const int* __restrict__ perm,
                          float* __restrict__ x1f, float* __restrict__ x2f,
                          unsigned short* __restrict__ x2b) {
  int c = blockIdx.x * 256 + threadIdx.x;  // grid.x = 8
  int row0 = blockIdx.y * 8;               // grid.y = 512
  int pc = perm[c];
#pragma unroll
  for (int r = 0; r < 8; ++r) {
    int row = row0 + r;
    float v = z[row * FEAT + pc];
    if (c < HALF) {
      x1f[row * HALF + c] = v;
    } else {
      x2f[row * HALF + c - HALF] = v;
      x2b[row * HALF + c - HALF] = f2bf(v);
    }
  }
}

// ---------------------------------------------------------------------------
// GEMM: C[4096 x N] = A[4096 x 1024] * Bt[N x 1024]^T   (bf16 in, fp32 acc)
// BK=32, 256 threads (4 waves). Round-0 proven loop: stage -> vmcnt(0) ->
// barrier -> 8/16 MFMA -> barrier.
// EPI=0: BM=64 tile (grid 512 = 2 WG/CU for latency overlap):
//        h = lrelu(C + b) -> bf16 hout.
// EPI=1: BM=128 tile, N=2048, pair-permuted cols; coupling epilogue fused
//        with NEXT depth's permutation: scatter y via invp into nx1/nx2/nx2b
//        (or contiguous to outz on the last depth).
// ---------------------------------------------------------------------------
template<int EPI>
__launch_bounds__(256)
__global__ void gemm_k(const unsigned short* __restrict__ A,
                       const unsigned short* __restrict__ Bt,
                       const float* __restrict__ bias,
                       const float* __restrict__ xin,
                       const int* __restrict__ invp,      // next-depth inverse perm (null = last depth)
                       float* __restrict__ nx1,
                       float* __restrict__ nx2,
                       unsigned short* __restrict__ nx2b,
                       float* __restrict__ outz,
                       int zbase,
                       unsigned short* __restrict__ ybf,
                       float* __restrict__ jac,
                       unsigned short* __restrict__ hout) {
  constexpr int BM = EPI ? 128 : 64;   // rows per block
  constexpr int MI = EPI ? 4 : 2;      // mfma row-tiles per wave
  constexpr int WR = EPI ? 64 : 32;    // rows per wave
  __shared__ unsigned short As[BM * 32];
  __shared__ unsigned short Bs[128 * 32];
  const int tid  = threadIdx.x;
  const int wave = tid >> 6, lane = tid & 63;
  const int quad = lane >> 4, l15 = lane & 15;
  const int wy = wave >> 1, wx = wave & 1;
  const int bm = blockIdx.y * BM;
  const int bn = blockIdx.x * 128;
  const int K = 1024;

  f32x4 acc[MI][4];
#pragma unroll
  for (int i = 0; i < MI; ++i)
#pragma unroll
    for (int j = 0; j < 4; ++j)
#pragma unroll
      for (int r = 0; r < 4; ++r) acc[i][j][r] = 0.0f;

  const int gbase = wave * 64 + lane;

  for (int kt = 0; kt < 32; ++kt) {
    const int k0 = kt * 32;
#pragma unroll
    for (int i = 0; i < BM / 64; ++i) {          // A granules: 1 or 2 per lane
      int g  = i * 256 + gbase;                  // granule id, 16B each
      int r  = g >> 2, kg = g & 3;
      async_cp16(&As[(i * 256 + wave * 64) * 8], A  + (size_t)(bm + r) * K + k0 + kg * 8);
    }
#pragma unroll
    for (int i = 0; i < 2; ++i) {                // B granules: always 2 per lane
      int g  = i * 256 + gbase;
      int r  = g >> 2, kg = g & 3;
      async_cp16(&Bs[(i * 256 + wave * 64) * 8], Bt + (size_t)(bn + r) * K + k0 + kg * 8);
    }
    asm volatile("s_waitcnt vmcnt(0)" ::: "memory");
    __syncthreads();

    bf16x8 af[MI], bf[4];
#pragma unroll
    for (int i = 0; i < MI; ++i)
      af[i] = lds_ld8(&As[(wy * WR + i * 16 + l15) * 32 + quad * 8]);
#pragma unroll
    for (int j = 0; j < 4; ++j)
      bf[j] = lds_ld8(&Bs[(wx * 64 + j * 16 + l15) * 32 + quad * 8]);
#pragma unroll
    for (int i = 0; i < MI; ++i)
#pragma unroll
      for (int j = 0; j < 4; ++j)
        acc[i][j] = __builtin_amdgcn_mfma_f32_16x16x32_bf16(af[i], bf[j], acc[i][j], 0, 0, 0);
    __syncthreads();
  }

  if (EPI == 0) {
    const int ldo = gridDim.x * 128;   // 1024
#pragma unroll
    for (int j = 0; j < 4; ++j) {
      int col = bn + wx * 64 + j * 16 + l15;
      float bj = bias[col];
#pragma unroll
      for (int i = 0; i < MI; ++i) {
#pragma unroll
        for (int r = 0; r < 4; ++r) {
          int row = bm + wy * WR + i * 16 + quad * 4 + r;
          float v = acc[i][j][r] + bj;
          v = v >= 0.0f ? v : 0.01f * v;
          hout[(size_t)row * ldo + col] = f2bf(v);
        }
      }
    }
  } else {
    const int g = (bn >> 6) + wx;   // 64-col group id in permuted space
    // per-j invariants (independent of i, r)
    float be[2], ba[2];
    int xcol[2], route[2];          // route: scatter destination col (or zcol for last depth)
#pragma unroll
    for (int j = 0; j < 2; ++j) {
      int pe = bn + wx * 64 + j * 16 + l15;
      be[j] = bias[pe];
      ba[j] = bias[pe + 32];
      xcol[j] = g * 32 + j * 16 + l15;
      int zcol = zbase + xcol[j];
      route[j] = invp ? invp[zcol] : zcol;
    }
#pragma unroll
    for (int i = 0; i < 4; ++i) {
      float esum[4] = {0.0f, 0.0f, 0.0f, 0.0f};
#pragma unroll
      for (int j = 0; j < 2; ++j) {
#pragma unroll
        for (int r = 0; r < 4; ++r) {
          int row = bm + wy * 64 + i * 16 + quad * 4 + r;
          float re = acc[i][j][r] + be[j];
          float ra = acc[i][j + 2][r] + ba[j];
          float e  = 1.2732395447351628f * atanf(0.5f * re);
          float y  = __expf(e) * xin[(size_t)row * HALF + xcol[j]] + ra;
          if (!invp) {
            outz[(size_t)row * FEAT + route[j]] = y;
          } else if (route[j] < HALF) {
            nx1[(size_t)row * HALF + route[j]] = y;
          } else {
            nx2[(size_t)row * HALF + route[j] - HALF] = y;
            nx2b[(size_t)row * HALF + route[j] - HALF] = f2bf(y);
          }
          if (ybf) ybf[(size_t)row * HALF + xcol[j]] = f2bf(y);
          esum[r] += e;
        }
      }
#pragma unroll
      for (int r = 0; r < 4; ++r) {
        float v = esum[r];
        v += __shfl_xor(v, 1);
        v += __shfl_xor(v, 2);
        v += __shfl_xor(v, 4);
        v += __shfl_xor(v, 8);
        if (l15 == 0) {
          int row = bm + wy * 64 + i * 16 + quad * 4 + r;
          atomicAdd(&jac[row], v);
        }
      }
    }
  }
}

__global__ void jcopy_k(const float* __restrict__ jac, float* __restrict__ out) {
  int i = blockIdx.x * 256 + threadIdx.x;
  if (i < 4096) out[i] = jac[i];
}

extern "C" void kernel_launch(void* const* d_in, const int* in_sizes, int n_in,
                              void* d_out, int out_size, void* d_ws, size_t ws_size,
                              hipStream_t stream) {
  const float* x     = (const float*)d_in[0];
  const int*   perms = (const int*)d_in[1];
  const float* s1w1  = (const float*)d_in[2];
  const float* s1b1  = (const float*)d_in[3];
  const float* s1w2  = (const float*)d_in[4];
  const float* s1b2  = (const float*)d_in[5];
  const float* s2w1  = (const float*)d_in[6];
  const float* s2b1  = (const float*)d_in[7];
  const float* s2w2  = (const float*)d_in[8];
  const float* s2b2  = (const float*)d_in[9];
  float* out = (float*)d_out;

  size_t off = 0;
  char* base = (char*)d_ws;
  auto alloc = [&](size_t bytes) {
    void* r = base + off;
    off += (bytes + 255) & ~(size_t)255;
    return r;
  };
  // ping-pong activation buffers (depth parity)
  float*          x1f[2]; float* x2f[2]; unsigned short* x2b[2];
  x1f[0] = (float*)alloc((size_t)MROWS * HALF * 4);
  x1f[1] = (float*)alloc((size_t)MROWS * HALF * 4);
  x2f[0] = (float*)alloc((size_t)MROWS * HALF * 4);
  x2f[1] = (float*)alloc((size_t)MROWS * HALF * 4);
  x2b[0] = (unsigned short*)alloc((size_t)MROWS * HALF * 2);
  x2b[1] = (unsigned short*)alloc((size_t)MROWS * HALF * 2);
  unsigned short* y1b = (unsigned short*)alloc((size_t)MROWS * HALF * 2);
  unsigned short* hb  = (unsigned short*)alloc((size_t)MROWS * HID * 2);
  // all-depth converted weights / biases / inverse perms
  unsigned short* w2a = (unsigned short*)alloc((size_t)DEPTH * HALF * HID * 2);
  unsigned short* w2b = (unsigned short*)alloc((size_t)DEPTH * FEAT * HID * 2);
  unsigned short* w1a = (unsigned short*)alloc((size_t)DEPTH * HALF * HID * 2);
  unsigned short* w1b = (unsigned short*)alloc((size_t)DEPTH * FEAT * HID * 2);
  float* b2a = (float*)alloc((size_t)DEPTH * 1024 * 4);
  float* b2b = (float*)alloc((size_t)DEPTH * 2048 * 4);
  float* b1a = (float*)alloc((size_t)DEPTH * 1024 * 4);
  float* b1b = (float*)alloc((size_t)DEPTH * 2048 * 4);
  int*   invp = (int*)alloc((size_t)DEPTH * FEAT * 4);
  float* jac = (float*)alloc(4096 * 4);

  hipMemsetAsync(jac, 0, 4096 * 4, stream);

  // precompute at full-device occupancy
  wcvt_k<<<dim3(64, 16, 4 * DEPTH), dim3(32, 8), 0, stream>>>(
      s2w1, s2w2, s1w1, s1w2, w2a, w2b, w1a, w1b);
  bias_k<<<(DEPTH * 6144 + 255) / 256, 256, 0, stream>>>(
      s2b1, s2b2, s1b1, s1b2, b2a, b2b, b1a, b1b);
  invp_k<<<(DEPTH * FEAT + 255) / 256, 256, 0, stream>>>(perms, invp);

  // depth-0 input permutation
  permute_k<<<dim3(8, 512), 256, 0, stream>>>(x, perms, x1f[0], x2f[0], x2b[0]);

  for (int d = 0; d < DEPTH; ++d) {
    const int par = d & 1, nxt = par ^ 1;
    const bool last = (d == DEPTH - 1);
    const int* ip = last ? nullptr : invp + (size_t)(d + 1) * FEAT;

    unsigned short* W2a = w2a + (size_t)d * HALF * HID;
    unsigned short* W2b = w2b + (size_t)d * FEAT * HID;
    unsigned short* W1a = w1a + (size_t)d * HALF * HID;
    unsigned short* W1b = w1b + (size_t)d * FEAT * HID;
    float* B2a = b2a + (size_t)d * 1024;
    float* B2b = b2b + (size_t)d * 2048;
    float* B1a = b1a + (size_t)d * 1024;
    float* B1b = b1b + (size_t)d * 2048;

    // subnet 2: r2 = lrelu(x2 @ w2a + b2a) @ w2b + b2b ; y1 = exp(e2)*x1 + r2_add
    gemm_k<0><<<dim3(8, 64), 256, 0, stream>>>(
        x2b[par], W2a, B2a, nullptr, nullptr, nullptr, nullptr, nullptr, nullptr, 0, nullptr, nullptr, hb);
    gemm_k<1><<<dim3(16, 32), 256, 0, stream>>>(
        hb, W2b, B2b, x1f[par], ip, x1f[nxt], x2f[nxt], x2b[nxt], out, 0, y1b, jac, nullptr);
    // subnet 1: r1 = lrelu(y1 @ w1a + b1a) @ w1b + b1b ; y2 = exp(e1)*x2 + r1_add
    gemm_k<0><<<dim3(8, 64), 256, 0, stream>>>(
        y1b, W1a, B1a, nullptr, nullptr, nullptr, nullptr, nullptr, nullptr, 0, nullptr, nullptr, hb);
    gemm_k<1><<<dim3(16, 32), 256, 0, stream>>>(
        hb, W1b, B1b, x2f[par], ip, x1f[nxt], x2f[nxt], x2b[nxt], out, HALF, nullptr, jac, nullptr);
  }
  jcopy_k<<<16, 256, 0, stream>>>(jac, out + (size_t)MROWS * FEAT);
}

// Round 4
// 4354.757 us; speedup vs baseline: 1.2040x; 1.2040x over previous
//
#include <hip/hip_runtime.h>
#include <stdint.h>

#define DEPTH 20
#define FEAT  2048
#define HALF  1024
#define HID   1024
#define MROWS 4096

typedef __bf16 bf16x8 __attribute__((ext_vector_type(8)));
typedef float  f32x4  __attribute__((ext_vector_type(4)));
typedef unsigned int u32x4 __attribute__((ext_vector_type(4)));

__device__ __forceinline__ unsigned short f2bf(float f) {
  union { float f; unsigned int u; } v; v.f = f;
  unsigned int u = v.u + 0x7fffu + ((v.u >> 16) & 1u);
  return (unsigned short)(u >> 16);
}

__device__ __forceinline__ void async_cp16(unsigned short* lds, const unsigned short* g) {
  __builtin_amdgcn_global_load_lds(
      (const __attribute__((address_space(1))) void*)g,
      (__attribute__((address_space(3))) void*)lds, 16, 0, 0);
}

__device__ __forceinline__ bf16x8 lds_ld8(const unsigned short* p) {
  return __builtin_bit_cast(bf16x8, *(const u32x4*)p);
}

// ---------------------------------------------------------------------------
// Batched (all 20 depths) weight transpose + cvt: src[k][n] fp32 -> dst[n'][k]
// bf16. 32x32 tiles (round-1-proven: 190us batched, 0 bank conflicts).
// For HID->FEAT matrices (pp=1) output rows are pair-permuted:
//   orig n<1024:  p = 64*(n/32) + (n%32)
//   orig n>=1024: p = 64*((n-1024)/32) + 32 + ((n-1024)%32)
// ---------------------------------------------------------------------------
__global__ void wcvt_k(const float* __restrict__ s2w1, const float* __restrict__ s2w2,
                       const float* __restrict__ s1w1, const float* __restrict__ s1w2,
                       unsigned short* __restrict__ w2a, unsigned short* __restrict__ w2b,
                       unsigned short* __restrict__ w1a, unsigned short* __restrict__ w1b) {
  const int zid = blockIdx.z;           // 0..79 : 20 depths x 4 matrices
  const int d = zid >> 2, which = zid & 3;
  const float* src; unsigned short* dst; int N, pp;
  switch (which) {
    case 0:  src = s2w1 + (size_t)d * HALF * HID;  dst = w2a + (size_t)d * HALF * HID; N = 1024; pp = 0; break;
    case 1:  src = s2w2 + (size_t)d * HID * FEAT;  dst = w2b + (size_t)d * FEAT * HID; N = 2048; pp = 1; break;
    case 2:  src = s1w1 + (size_t)d * HALF * HID;  dst = w1a + (size_t)d * HALF * HID; N = 1024; pp = 0; break;
    default: src = s1w2 + (size_t)d * HID * FEAT;  dst = w1b + (size_t)d * FEAT * HID; N = 2048; pp = 1; break;
  }
  int nb = blockIdx.x * 32;
  if (nb >= N) return;
  int kb = blockIdx.y * 32;
  __shared__ float t[32][33];
  int tx = threadIdx.x, ty = threadIdx.y;
#pragma unroll
  for (int s = 0; s < 4; ++s)
    t[ty + 8*s][tx] = src[(size_t)(kb + ty + 8*s) * N + nb + tx];
  __syncthreads();
  int pbase = pp ? (nb < 1024 ? 2*nb : 2*(nb - 1024) + 32) : nb;
#pragma unroll
  for (int s = 0; s < 4; ++s) {
    int nl = ty + 8*s;
    dst[(size_t)(pbase + nl) * 1024 + kb + tx] = f2bf(t[tx][nl]);
  }
}

__device__ __forceinline__ int porig(int p) {
  int g = p >> 6, o = p & 63;
  return (o < 32) ? (g*32 + o) : (1024 + g*32 + (o - 32));
}

// Batched over all depths: i in [0, 20*6144)
__global__ void bias_k(const float* __restrict__ s2b1, const float* __restrict__ s2b2,
                       const float* __restrict__ s1b1, const float* __restrict__ s1b2,
                       float* __restrict__ b2a, float* __restrict__ b2b,
                       float* __restrict__ b1a, float* __restrict__ b1b) {
  int i = blockIdx.x * 256 + threadIdx.x;
  if (i >= DEPTH * 6144) return;
  int d = i / 6144, j = i - d * 6144;
  if (j < 1024)      b2a[d*1024 + j] = s2b1[(size_t)d*HID + j];
  else if (j < 3072) { int p = j - 1024; b2b[d*2048 + p] = s2b2[(size_t)d*FEAT + porig(p)]; }
  else if (j < 4096) b1a[d*1024 + j - 3072] = s1b1[(size_t)d*HID + j - 3072];
  else               { int p = j - 4096; b1b[d*2048 + p] = s1b2[(size_t)d*FEAT + porig(p)]; }
}

// z -> permuted split: x1 fp32, x2 fp32 + bf16 (round-0 proven:
// coalesced writes, gathered reads served by L2/L3-resident z)
__global__ void permute_k(const float* __restrict__ z, const int* __restrict__ perm,
                          float* __restrict__ x1f, float* __restrict__ x2f,
                          unsigned short* __restrict__ x2b) {
  int c = blockIdx.x * 256 + threadIdx.x;  // grid.x = 8
  int row0 = blockIdx.y * 8;               // grid.y = 512
  int pc = perm[c];
#pragma unroll
  for (int r = 0; r < 8; ++r) {
    int row = row0 + r;
    float v = z[row * FEAT + pc];
    if (c < HALF) {
      x1f[row * HALF + c] = v;
    } else {
      x2f[row * HALF + c - HALF] = v;
      x2b[row * HALF + c - HALF] = f2bf(v);
    }
  }
}

// ---------------------------------------------------------------------------
// GEMM: C[4096 x N] = A[4096 x 1024] * Bt[N x 1024]^T   (bf16 in, fp32 acc)
// 128x128 tile, BK=32, 256 threads (4 waves, 2x2, 64x64 each, 4x4 mfma grid).
// 2-buffer pipeline, T3-minimal recipe (§5.5, m230): stage(kt+1) issued
// BEFORE the ds_read+MFMA of tile kt; ONE __syncthreads per K-step supplies
// the vmcnt(0)/lgkmcnt(0) drain + barrier. Pure HIP, no inline asm.
// EPI=0: h = lrelu(C + b) -> bf16 hout (N = gridDim.x*128)
// EPI=1: coupling epilogue, N=2048, pair-permuted cols:
//        acc[i][j] (j<2) = e-col, acc[i][j+2] = its additive partner.
// ---------------------------------------------------------------------------
template<int EPI>
__launch_bounds__(256)
__global__ void gemm_k(const unsigned short* __restrict__ A,
                       const unsigned short* __restrict__ Bt,
                       const float* __restrict__ bias,
                       const float* __restrict__ xin,
                       float* __restrict__ yout,
                       unsigned short* __restrict__ ybf,
                       float* __restrict__ jac,
                       unsigned short* __restrict__ hout) {
  __shared__ unsigned short As[2][128 * 32];
  __shared__ unsigned short Bs[2][128 * 32];
  const int tid  = threadIdx.x;
  const int wave = tid >> 6, lane = tid & 63;
  const int quad = lane >> 4, l15 = lane & 15;
  const int wy = wave >> 1, wx = wave & 1;
  const int bm = blockIdx.y * 128;
  const int bn = blockIdx.x * 128;
  const int K = 1024;

  f32x4 acc[4][4];
#pragma unroll
  for (int i = 0; i < 4; ++i)
#pragma unroll
    for (int j = 0; j < 4; ++j)
#pragma unroll
      for (int r = 0; r < 4; ++r) acc[i][j][r] = 0.0f;

  const int gbase = wave * 64 + lane;

  // 4 global_load_lds per lane per call (2 A granules + 2 B granules)
  auto stage = [&](int kt, int buf) {
    const int k0 = kt * 32;
#pragma unroll
    for (int i = 0; i < 2; ++i) {
      int g  = i * 256 + gbase;          // granule id, 16B each
      int r  = g >> 2, kg = g & 3;
      async_cp16(&As[buf][(i * 256 + wave * 64) * 8], A  + (size_t)(bm + r) * K + k0 + kg * 8);
      async_cp16(&Bs[buf][(i * 256 + wave * 64) * 8], Bt + (size_t)(bn + r) * K + k0 + kg * 8);
    }
  };

  stage(0, 0);
  __syncthreads();   // drain stage(0); buf 0 readable

  for (int kt = 0; kt < 32; ++kt) {
    const int cur = kt & 1;
    if (kt < 31) stage(kt + 1, cur ^ 1);   // issue next tile first (overlaps compute)

    bf16x8 af[4], bf[4];
#pragma unroll
    for (int i = 0; i < 4; ++i)
      af[i] = lds_ld8(&As[cur][(wy * 64 + i * 16 + l15) * 32 + quad * 8]);
#pragma unroll
    for (int j = 0; j < 4; ++j)
      bf[j] = lds_ld8(&Bs[cur][(wx * 64 + j * 16 + l15) * 32 + quad * 8]);
#pragma unroll
    for (int i = 0; i < 4; ++i)
#pragma unroll
      for (int j = 0; j < 4; ++j)
        acc[i][j] = __builtin_amdgcn_mfma_f32_16x16x32_bf16(af[i], bf[j], acc[i][j], 0, 0, 0);

    __syncthreads();  // vmcnt(0)+lgkmcnt(0)+barrier: next buf staged, cur reads done
  }

  if (EPI == 0) {
    const int ldo = gridDim.x * 128;   // 1024
#pragma unroll
    for (int j = 0; j < 4; ++j) {
      int col = bn + wx * 64 + j * 16 + l15;
      float bj = bias[col];
#pragma unroll
      for (int i = 0; i < 4; ++i) {
#pragma unroll
        for (int r = 0; r < 4; ++r) {
          int row = bm + wy * 64 + i * 16 + quad * 4 + r;
          float v = acc[i][j][r] + bj;
          v = v >= 0.0f ? v : 0.01f * v;
          hout[(size_t)row * ldo + col] = f2bf(v);
        }
      }
    }
  } else {
    const int g = (bn >> 6) + wx;   // 64-col group id in permuted space
#pragma unroll
    for (int i = 0; i < 4; ++i) {
      float esum[4] = {0.0f, 0.0f, 0.0f, 0.0f};
#pragma unroll
      for (int j = 0; j < 2; ++j) {
        int pe = bn + wx * 64 + j * 16 + l15;   // e-col (permuted)
        float be = bias[pe];
        float ba = bias[pe + 32];
        int xcol = g * 32 + j * 16 + l15;        // original col in [0,1024)
#pragma unroll
        for (int r = 0; r < 4; ++r) {
          int row = bm + wy * 64 + i * 16 + quad * 4 + r;
          float re = acc[i][j][r] + be;
          float ra = acc[i][j + 2][r] + ba;
          float e  = 1.2732395447351628f * atanf(0.5f * re);
          float y  = __expf(e) * xin[(size_t)row * HALF + xcol] + ra;
          yout[(size_t)row * FEAT + xcol] = y;
          if (ybf) ybf[(size_t)row * HALF + xcol] = f2bf(y);
          esum[r] += e;
        }
      }
#pragma unroll
      for (int r = 0; r < 4; ++r) {
        float v = esum[r];
        v += __shfl_xor(v, 1);
        v += __shfl_xor(v, 2);
        v += __shfl_xor(v, 4);
        v += __shfl_xor(v, 8);
        if (l15 == 0) {
          int row = bm + wy * 64 + i * 16 + quad * 4 + r;
          atomicAdd(&jac[row], v);
        }
      }
    }
  }
}

__global__ void jcopy_k(const float* __restrict__ jac, float* __restrict__ out) {
  int i = blockIdx.x * 256 + threadIdx.x;
  if (i < 4096) out[i] = jac[i];
}

extern "C" void kernel_launch(void* const* d_in, const int* in_sizes, int n_in,
                              void* d_out, int out_size, void* d_ws, size_t ws_size,
                              hipStream_t stream) {
  const float* x     = (const float*)d_in[0];
  const int*   perms = (const int*)d_in[1];
  const float* s1w1  = (const float*)d_in[2];
  const float* s1b1  = (const float*)d_in[3];
  const float* s1w2  = (const float*)d_in[4];
  const float* s1b2  = (const float*)d_in[5];
  const float* s2w1  = (const float*)d_in[6];
  const float* s2b1  = (const float*)d_in[7];
  const float* s2w2  = (const float*)d_in[8];
  const float* s2b2  = (const float*)d_in[9];
  float* out = (float*)d_out;

  size_t off = 0;
  char* base = (char*)d_ws;
  auto alloc = [&](size_t bytes) {
    void* r = base + off;
    off += (bytes + 255) & ~(size_t)255;
    return r;
  };
  float*          x1f = (float*)alloc((size_t)MROWS * HALF * 4);
  float*          x2f = (float*)alloc((size_t)MROWS * HALF * 4);
  unsigned short* x2b = (unsigned short*)alloc((size_t)MROWS * HALF * 2);
  unsigned short* y1b = (unsigned short*)alloc((size_t)MROWS * HALF * 2);
  unsigned short* hb  = (unsigned short*)alloc((size_t)MROWS * HID * 2);
  float*          zbuf= (float*)alloc((size_t)MROWS * FEAT * 4);
  // all-depth converted weights / biases
  unsigned short* w2a = (unsigned short*)alloc((size_t)DEPTH * HALF * HID * 2);
  unsigned short* w2b = (unsigned short*)alloc((size_t)DEPTH * FEAT * HID * 2);
  unsigned short* w1a = (unsigned short*)alloc((size_t)DEPTH * HALF * HID * 2);
  unsigned short* w1b = (unsigned short*)alloc((size_t)DEPTH * FEAT * HID * 2);
  float* b2a = (float*)alloc((size_t)DEPTH * 1024 * 4);
  float* b2b = (float*)alloc((size_t)DEPTH * 2048 * 4);
  float* b1a = (float*)alloc((size_t)DEPTH * 1024 * 4);
  float* b1b = (float*)alloc((size_t)DEPTH * 2048 * 4);
  float* jac = (float*)alloc(4096 * 4);

  hipMemsetAsync(jac, 0, 4096 * 4, stream);

  // convert everything up-front at full-device occupancy
  wcvt_k<<<dim3(64, 32, 4 * DEPTH), dim3(32, 8), 0, stream>>>(
      s2w1, s2w2, s1w1, s1w2, w2a, w2b, w1a, w1b);
  bias_k<<<(DEPTH * 6144 + 255) / 256, 256, 0, stream>>>(
      s2b1, s2b2, s1b1, s1b2, b2a, b2b, b1a, b1b);

  for (int d = 0; d < DEPTH; ++d) {
    const float* zsrc = (d == 0) ? x : zbuf;
    permute_k<<<dim3(8, 512), 256, 0, stream>>>(zsrc, perms + (size_t)d * FEAT, x1f, x2f, x2b);

    unsigned short* W2a = w2a + (size_t)d * HALF * HID;
    unsigned short* W2b = w2b + (size_t)d * FEAT * HID;
    unsigned short* W1a = w1a + (size_t)d * HALF * HID;
    unsigned short* W1b = w1b + (size_t)d * FEAT * HID;
    float* B2a = b2a + (size_t)d * 1024;
    float* B2b = b2b + (size_t)d * 2048;
    float* B1a = b1a + (size_t)d * 1024;
    float* B1b = b1b + (size_t)d * 2048;

    float* zdst = (d == DEPTH - 1) ? out : zbuf;
    // subnet 2: r2 = lrelu(x2 @ w2a + b2a) @ w2b + b2b ; y1 = exp(e2)*x1 + r2_add
    gemm_k<0><<<dim3(8, 32), 256, 0, stream>>>(x2b, W2a, B2a, nullptr, nullptr, nullptr, nullptr, hb);
    gemm_k<1><<<dim3(16, 32), 256, 0, stream>>>(hb, W2b, B2b, x1f, zdst, y1b, jac, nullptr);
    // subnet 1: r1 = lrelu(y1 @ w1a + b1a) @ w1b + b1b ; y2 = exp(e1)*x2 + r1_add
    gemm_k<0><<<dim3(8, 32), 256, 0, stream>>>(y1b, W1a, B1a, nullptr, nullptr, nullptr, nullptr, hb);
    gemm_k<1><<<dim3(16, 32), 256, 0, stream>>>(hb, W1b, B1b, x2f, zdst + HALF, nullptr, jac, nullptr);
  }
  jcopy_k<<<16, 256, 0, stream>>>(jac, out + (size_t)MROWS * FEAT);
}

// Round 5
// 3503.080 us; speedup vs baseline: 1.4967x; 1.2431x over previous
//
#include <hip/hip_runtime.h>
#include <stdint.h>

#define DEPTH 20
#define FEAT  2048
#define HALF  1024
#define HID   1024
#define MROWS 4096

typedef __bf16 bf16x8 __attribute__((ext_vector_type(8)));
typedef float  f32x4  __attribute__((ext_vector_type(4)));
typedef unsigned int u32x4 __attribute__((ext_vector_type(4)));

__device__ __forceinline__ unsigned short f2bf(float f) {
  union { float f; unsigned int u; } v; v.f = f;
  unsigned int u = v.u + 0x7fffu + ((v.u >> 16) & 1u);
  return (unsigned short)(u >> 16);
}

__device__ __forceinline__ void async_cp16(unsigned short* lds, const unsigned short* g) {
  __builtin_amdgcn_global_load_lds(
      (const __attribute__((address_space(1))) void*)g,
      (__attribute__((address_space(3))) void*)lds, 16, 0, 0);
}

__device__ __forceinline__ bf16x8 lds_ld8(const unsigned short* p) {
  return __builtin_bit_cast(bf16x8, *(const u32x4*)p);
}

// ---------------------------------------------------------------------------
// Batched (all 20 depths) weight transpose + cvt: src[k][n] fp32 -> dst[n'][k]
// bf16. 32x32 tiles (proven: ~190us batched, 0 bank conflicts).
// For HID->FEAT matrices (pp=1) output rows are pair-permuted:
//   orig n<1024:  p = 64*(n/32) + (n%32)
//   orig n>=1024: p = 64*((n-1024)/32) + 32 + ((n-1024)%32)
// ---------------------------------------------------------------------------
__global__ void wcvt_k(const float* __restrict__ s2w1, const float* __restrict__ s2w2,
                       const float* __restrict__ s1w1, const float* __restrict__ s1w2,
                       unsigned short* __restrict__ w2a, unsigned short* __restrict__ w2b,
                       unsigned short* __restrict__ w1a, unsigned short* __restrict__ w1b) {
  const int zid = blockIdx.z;           // 0..79 : 20 depths x 4 matrices
  const int d = zid >> 2, which = zid & 3;
  const float* src; unsigned short* dst; int N, pp;
  switch (which) {
    case 0:  src = s2w1 + (size_t)d * HALF * HID;  dst = w2a + (size_t)d * HALF * HID; N = 1024; pp = 0; break;
    case 1:  src = s2w2 + (size_t)d * HID * FEAT;  dst = w2b + (size_t)d * FEAT * HID; N = 2048; pp = 1; break;
    case 2:  src = s1w1 + (size_t)d * HALF * HID;  dst = w1a + (size_t)d * HALF * HID; N = 1024; pp = 0; break;
    default: src = s1w2 + (size_t)d * HID * FEAT;  dst = w1b + (size_t)d * FEAT * HID; N = 2048; pp = 1; break;
  }
  int nb = blockIdx.x * 32;
  if (nb >= N) return;
  int kb = blockIdx.y * 32;
  __shared__ float t[32][33];
  int tx = threadIdx.x, ty = threadIdx.y;
#pragma unroll
  for (int s = 0; s < 4; ++s)
    t[ty + 8*s][tx] = src[(size_t)(kb + ty + 8*s) * N + nb + tx];
  __syncthreads();
  int pbase = pp ? (nb < 1024 ? 2*nb : 2*(nb - 1024) + 32) : nb;
#pragma unroll
  for (int s = 0; s < 4; ++s) {
    int nl = ty + 8*s;
    dst[(size_t)(pbase + nl) * 1024 + kb + tx] = f2bf(t[tx][nl]);
  }
}

__device__ __forceinline__ int porig(int p) {
  int g = p >> 6, o = p & 63;
  return (o < 32) ? (g*32 + o) : (1024 + g*32 + (o - 32));
}

// Batched over all depths: i in [0, 20*6144)
__global__ void bias_k(const float* __restrict__ s2b1, const float* __restrict__ s2b2,
                       const float* __restrict__ s1b1, const float* __restrict__ s1b2,
                       float* __restrict__ b2a, float* __restrict__ b2b,
                       float* __restrict__ b1a, float* __restrict__ b1b) {
  int i = blockIdx.x * 256 + threadIdx.x;
  if (i >= DEPTH * 6144) return;
  int d = i / 6144, j = i - d * 6144;
  if (j < 1024)      b2a[d*1024 + j] = s2b1[(size_t)d*HID + j];
  else if (j < 3072) { int p = j - 1024; b2b[d*2048 + p] = s2b2[(size_t)d*FEAT + porig(p)]; }
  else if (j < 4096) b1a[d*1024 + j - 3072] = s1b1[(size_t)d*HID + j - 3072];
  else               { int p = j - 4096; b1b[d*2048 + p] = s1b2[(size_t)d*FEAT + porig(p)]; }
}

// z -> permuted split: x1 fp32, x2 fp32 + bf16 (round-0 proven:
// coalesced writes, gathered reads served by L2/L3-resident z)
__global__ void permute_k(const float* __restrict__ z, const int* __restrict__ perm,
                          float* __restrict__ x1f, float* __restrict__ x2f,
                          unsigned short* __restrict__ x2b) {
  int c = blockIdx.x * 256 + threadIdx.x;  // grid.x = 8
  int row0 = blockIdx.y * 8;               // grid.y = 512
  int pc = perm[c];
#pragma unroll
  for (int r = 0; r < 8; ++r) {
    int row = row0 + r;
    float v = z[row * FEAT + pc];
    if (c < HALF) {
      x1f[row * HALF + c] = v;
    } else {
      x2f[row * HALF + c - HALF] = v;
      x2b[row * HALF + c - HALF] = f2bf(v);
    }
  }
}

// ---------------------------------------------------------------------------
// GEMM: C[4096 x N] = A[4096 x 1024] * Bt[N x 1024]^T   (bf16 in, fp32 acc)
// 64x128 tile, BK=64, 256 threads (4 waves 2x2; wave = 32 rows x 64 cols,
// 2x4 mfma frags). ROUND-0 PROVEN SCHEDULE: stage -> vmcnt(0) -> barrier ->
// compute -> barrier (single buffer; co-resident WGs supply overlap, m114).
// Geometry changes vs round 0: BM 128->64 (2-4 WGs/CU), BK 32->64 (half the
// drain events), XOR-swizzled LDS chunks via pre-swizzled global source
// (m173/T2: kg ^= r&7 on stage, chunk ^= row&7 on read -> 2-way = free).
// EPI=0: h = lrelu(C + b) -> bf16 hout (N = gridDim.x*128)
// EPI=1: coupling epilogue, N=2048, pair-permuted cols:
//        acc[i][j] (j<2) = e-col, acc[i][j+2] = its additive partner.
// ---------------------------------------------------------------------------
template<int EPI>
__launch_bounds__(256)
__global__ void gemm_k(const unsigned short* __restrict__ A,
                       const unsigned short* __restrict__ Bt,
                       const float* __restrict__ bias,
                       const float* __restrict__ xin,
                       float* __restrict__ yout,
                       unsigned short* __restrict__ ybf,
                       float* __restrict__ jac,
                       unsigned short* __restrict__ hout) {
  __shared__ unsigned short As[64 * 64];    // 8 KB
  __shared__ unsigned short Bs[128 * 64];   // 16 KB
  const int tid  = threadIdx.x;
  const int wave = tid >> 6, lane = tid & 63;
  const int quad = lane >> 4, l15 = lane & 15;
  const int wy = wave >> 1, wx = wave & 1;
  const int bm = blockIdx.y * 64;
  const int bn = blockIdx.x * 128;
  const int K = 1024;

  f32x4 acc[2][4];
#pragma unroll
  for (int i = 0; i < 2; ++i)
#pragma unroll
    for (int j = 0; j < 4; ++j)
#pragma unroll
      for (int r = 0; r < 4; ++r) acc[i][j][r] = 0.0f;

  const int gbase = wave * 64 + lane;

  for (int kt = 0; kt < 16; ++kt) {
    const int k0 = kt * 64;
    // A tile 64x64: 512 granules of 16B, 2 per lane. Row r = g>>3, chunk
    // kg = g&7; source chunk pre-swizzled by r&7 so swizzled read is linear.
#pragma unroll
    for (int i = 0; i < 2; ++i) {
      int g  = i * 256 + gbase;
      int r  = g >> 3, kg = (g & 7) ^ (r & 7);
      async_cp16(&As[(i * 256 + wave * 64) * 8], A + (size_t)(bm + r) * K + k0 + kg * 8);
    }
    // B tile 128x64: 1024 granules, 4 per lane.
#pragma unroll
    for (int i = 0; i < 4; ++i) {
      int g  = i * 256 + gbase;
      int r  = g >> 3, kg = (g & 7) ^ (r & 7);
      async_cp16(&Bs[(i * 256 + wave * 64) * 8], Bt + (size_t)(bn + r) * K + k0 + kg * 8);
    }
    asm volatile("s_waitcnt vmcnt(0)" ::: "memory");
    __syncthreads();

#pragma unroll
    for (int kk = 0; kk < 2; ++kk) {
      bf16x8 af[2], bf[4];
#pragma unroll
      for (int i = 0; i < 2; ++i) {
        int ar = wy * 32 + i * 16 + l15;
        af[i] = lds_ld8(&As[ar * 64 + (((kk * 4 + quad) ^ (ar & 7))) * 8]);
      }
#pragma unroll
      for (int j = 0; j < 4; ++j) {
        int br = wx * 64 + j * 16 + l15;
        bf[j] = lds_ld8(&Bs[br * 64 + (((kk * 4 + quad) ^ (br & 7))) * 8]);
      }
#pragma unroll
      for (int i = 0; i < 2; ++i)
#pragma unroll
        for (int j = 0; j < 4; ++j)
          acc[i][j] = __builtin_amdgcn_mfma_f32_16x16x32_bf16(af[i], bf[j], acc[i][j], 0, 0, 0);
    }
    __syncthreads();
  }

  if (EPI == 0) {
    const int ldo = gridDim.x * 128;   // 1024
#pragma unroll
    for (int j = 0; j < 4; ++j) {
      int col = bn + wx * 64 + j * 16 + l15;
      float bj = bias[col];
#pragma unroll
      for (int i = 0; i < 2; ++i) {
#pragma unroll
        for (int r = 0; r < 4; ++r) {
          int row = bm + wy * 32 + i * 16 + quad * 4 + r;
          float v = acc[i][j][r] + bj;
          v = v >= 0.0f ? v : 0.01f * v;
          hout[(size_t)row * ldo + col] = f2bf(v);
        }
      }
    }
  } else {
    const int g = (bn >> 6) + wx;   // 64-col group id in permuted space
#pragma unroll
    for (int i = 0; i < 2; ++i) {
      float esum[4] = {0.0f, 0.0f, 0.0f, 0.0f};
#pragma unroll
      for (int j = 0; j < 2; ++j) {
        int pe = bn + wx * 64 + j * 16 + l15;   // e-col (permuted)
        float be = bias[pe];
        float ba = bias[pe + 32];
        int xcol = g * 32 + j * 16 + l15;        // original col in [0,1024)
#pragma unroll
        for (int r = 0; r < 4; ++r) {
          int row = bm + wy * 32 + i * 16 + quad * 4 + r;
          float re = acc[i][j][r] + be;
          float ra = acc[i][j + 2][r] + ba;
          float e  = 1.2732395447351628f * atanf(0.5f * re);
          float y  = __expf(e) * xin[(size_t)row * HALF + xcol] + ra;
          yout[(size_t)row * FEAT + xcol] = y;
          if (ybf) ybf[(size_t)row * HALF + xcol] = f2bf(y);
          esum[r] += e;
        }
      }
#pragma unroll
      for (int r = 0; r < 4; ++r) {
        float v = esum[r];
        v += __shfl_xor(v, 1);
        v += __shfl_xor(v, 2);
        v += __shfl_xor(v, 4);
        v += __shfl_xor(v, 8);
        if (l15 == 0) {
          int row = bm + wy * 32 + i * 16 + quad * 4 + r;
          atomicAdd(&jac[row], v);
        }
      }
    }
  }
}

__global__ void jcopy_k(const float* __restrict__ jac, float* __restrict__ out) {
  int i = blockIdx.x * 256 + threadIdx.x;
  if (i < 4096) out[i] = jac[i];
}

extern "C" void kernel_launch(void* const* d_in, const int* in_sizes, int n_in,
                              void* d_out, int out_size, void* d_ws, size_t ws_size,
                              hipStream_t stream) {
  const float* x     = (const float*)d_in[0];
  const int*   perms = (const int*)d_in[1];
  const float* s1w1  = (const float*)d_in[2];
  const float* s1b1  = (const float*)d_in[3];
  const float* s1w2  = (const float*)d_in[4];
  const float* s1b2  = (const float*)d_in[5];
  const float* s2w1  = (const float*)d_in[6];
  const float* s2b1  = (const float*)d_in[7];
  const float* s2w2  = (const float*)d_in[8];
  const float* s2b2  = (const float*)d_in[9];
  float* out = (float*)d_out;

  size_t off = 0;
  char* base = (char*)d_ws;
  auto alloc = [&](size_t bytes) {
    void* r = base + off;
    off += (bytes + 255) & ~(size_t)255;
    return r;
  };
  float*          x1f = (float*)alloc((size_t)MROWS * HALF * 4);
  float*          x2f = (float*)alloc((size_t)MROWS * HALF * 4);
  unsigned short* x2b = (unsigned short*)alloc((size_t)MROWS * HALF * 2);
  unsigned short* y1b = (unsigned short*)alloc((size_t)MROWS * HALF * 2);
  unsigned short* hb  = (unsigned short*)alloc((size_t)MROWS * HID * 2);
  float*          zbuf= (float*)alloc((size_t)MROWS * FEAT * 4);
  // all-depth converted weights / biases
  unsigned short* w2a = (unsigned short*)alloc((size_t)DEPTH * HALF * HID * 2);
  unsigned short* w2b = (unsigned short*)alloc((size_t)DEPTH * FEAT * HID * 2);
  unsigned short* w1a = (unsigned short*)alloc((size_t)DEPTH * HALF * HID * 2);
  unsigned short* w1b = (unsigned short*)alloc((size_t)DEPTH * FEAT * HID * 2);
  float* b2a = (float*)alloc((size_t)DEPTH * 1024 * 4);
  float* b2b = (float*)alloc((size_t)DEPTH * 2048 * 4);
  float* b1a = (float*)alloc((size_t)DEPTH * 1024 * 4);
  float* b1b = (float*)alloc((size_t)DEPTH * 2048 * 4);
  float* jac = (float*)alloc(4096 * 4);

  hipMemsetAsync(jac, 0, 4096 * 4, stream);

  // convert everything up-front at full-device occupancy
  wcvt_k<<<dim3(64, 32, 4 * DEPTH), dim3(32, 8), 0, stream>>>(
      s2w1, s2w2, s1w1, s1w2, w2a, w2b, w1a, w1b);
  bias_k<<<(DEPTH * 6144 + 255) / 256, 256, 0, stream>>>(
      s2b1, s2b2, s1b1, s1b2, b2a, b2b, b1a, b1b);

  for (int d = 0; d < DEPTH; ++d) {
    const float* zsrc = (d == 0) ? x : zbuf;
    permute_k<<<dim3(8, 512), 256, 0, stream>>>(zsrc, perms + (size_t)d * FEAT, x1f, x2f, x2b);

    unsigned short* W2a = w2a + (size_t)d * HALF * HID;
    unsigned short* W2b = w2b + (size_t)d * FEAT * HID;
    unsigned short* W1a = w1a + (size_t)d * HALF * HID;
    unsigned short* W1b = w1b + (size_t)d * FEAT * HID;
    float* B2a = b2a + (size_t)d * 1024;
    float* B2b = b2b + (size_t)d * 2048;
    float* B1a = b1a + (size_t)d * 1024;
    float* B1b = b1b + (size_t)d * 2048;

    float* zdst = (d == DEPTH - 1) ? out : zbuf;
    // subnet 2: r2 = lrelu(x2 @ w2a + b2a) @ w2b + b2b ; y1 = exp(e2)*x1 + r2_add
    gemm_k<0><<<dim3(8, 64), 256, 0, stream>>>(x2b, W2a, B2a, nullptr, nullptr, nullptr, nullptr, hb);
    gemm_k<1><<<dim3(16, 64), 256, 0, stream>>>(hb, W2b, B2b, x1f, zdst, y1b, jac, nullptr);
    // subnet 1: r1 = lrelu(y1 @ w1a + b1a) @ w1b + b1b ; y2 = exp(e1)*x2 + r1_add
    gemm_k<0><<<dim3(8, 64), 256, 0, stream>>>(y1b, W1a, B1a, nullptr, nullptr, nullptr, nullptr, hb);
    gemm_k<1><<<dim3(16, 64), 256, 0, stream>>>(hb, W1b, B1b, x2f, zdst + HALF, nullptr, jac, nullptr);
  }
  jcopy_k<<<16, 256, 0, stream>>>(jac, out + (size_t)MROWS * FEAT);
}